// Round 5
// baseline (2105.008 us; speedup 1.0000x reference)
//
#include <hip/hip_runtime.h>

// LSTMPredictor: B=1024, T=512, IN=19, H=128, OUT=7 (fp32 in/out)
// FUSED persistent kernel: 256 blocks x 512 threads, R=4 rows/block.
// Waves 0-3: layer1 (32 cols each, weights in VGPRs) + y-duty on wave 0.
// Waves 4-7: layer2, one step behind, wh2 in VGPRs, wi2 read from LDS.
// h1/h2 in 2KB LDS double buffers (no HBM round trip). 513 barriers total.
// D-layout row-duplication invariant (R3): A-frag rows duplicate mod 4 ->
// acc_g[r] at every lane holds D_g[r][col]; lane (lg,lc) selects reg lg.

typedef _Float16 half8 __attribute__((ext_vector_type(8)));
typedef float f32x4 __attribute__((ext_vector_type(4)));

#define MFMA16(a, b, c) __builtin_amdgcn_mfma_f32_16x16x32_f16((a), (b), (c), 0, 0, 0)
#define BARRIER() asm volatile("s_waitcnt lgkmcnt(0)\ns_barrier" ::: "memory")

__device__ __forceinline__ float sigf(float x) {
  return __builtin_amdgcn_rcpf(1.f + __expf(-x));   // NaN-free at +/-inf
}
__device__ __forceinline__ float tanhf_(float x) {
  return 1.f - 2.f * __builtin_amdgcn_rcpf(1.f + __expf(2.f * x));  // NaN-free
}
// acc_g[r] == D_g[r][lc] at every lane (duplication invariant) -> pick reg lg.
__device__ __forceinline__ float sel4(const f32x4 a, const int lg) {
  const float v01 = (lg & 1) ? a[1] : a[0];
  const float v23 = (lg & 1) ? a[3] : a[2];
  return (lg & 2) ? v23 : v01;
}

// ---- pre-pass: x fp32 -> fp16 A-frag layout xp[b][t][cg][j], cg=cc*4+rr ----
__global__ __launch_bounds__(256) void xpad_kernel(const float* __restrict__ x,
                                                   _Float16* __restrict__ xp) {
  const int idx = blockIdx.x * 256 + threadIdx.x;
  if (idx >= 256 * 512 * 12) return;
  const int cg = idx % 12, bt = idx / 12;
  const int b = bt >> 9, t = bt & 511;
  const int cc = cg >> 2, rr = cg & 3;
  const float* src = x + ((size_t)(b * 4 + rr) * 512 + t) * 19 + cc * 8;
  _Float16* dst = xp + (size_t)idx * 8;
#pragma unroll
  for (int j = 0; j < 8; ++j)
    dst[j] = (_Float16)((cc * 8 + j < 19) ? src[j] : 0.f);
}

__global__ __launch_bounds__(512) void lstm_fused_kernel(
    const _Float16* __restrict__ xp,    // [256][512][12][8] fp16
    const float* __restrict__ Wih1,     // [512,19]
    const float* __restrict__ Whh1,     // [512,128]
    const float* __restrict__ bih1, const float* __restrict__ bhh1,
    const float* __restrict__ Wih2,     // [512,128]
    const float* __restrict__ Whh2,     // [512,128]
    const float* __restrict__ bih2, const float* __restrict__ bhh2,
    const float* __restrict__ Wlin,     // [7,128]
    const float* __restrict__ blin,     // [7]
    float* __restrict__ out)            // [1024, 3584]
{
  __shared__ _Float16 wils[528 * 132];  // 139,392 B: wi2 rows 0-511, Wlin rows 512-527
  __shared__ _Float16 h1b[2048];        // double buffer, frag layout
  __shared__ _Float16 h2b[2048];
  const int tid = threadIdx.x, bid = blockIdx.x;
  const int wv = tid >> 6, lane = tid & 63;
  const int lg = lane >> 4, lc = lane & 15;
  const int off0 = lg * 32 + (lc & 3) * 8;   // A-frag read offset (halfs)

  // Stage wi2 + Wlin into LDS (stride 132 -> 264B rows: 2-way banks, free).
  for (int i = tid; i < 512 * 128; i += 512)
    wils[(i >> 7) * 132 + (i & 127)] = (_Float16)Wih2[i];
  for (int i = tid; i < 16 * 128; i += 512)
    wils[(512 + (i >> 7)) * 132 + (i & 127)] = (_Float16)((i < 7 * 128) ? Wlin[i] : 0.f);
  for (int i = tid; i < 2048; i += 512) {
    h1b[i] = (_Float16)0.f;
    h2b[i] = (_Float16)0.f;
  }
  __syncthreads();

  const f32x4 fz = {0.f, 0.f, 0.f, 0.f};

  if (wv < 4) {
    // ---------------- Layer-1 role (+ y duty on wave 0) ----------------
    const int wbase = wv * 32;
    half8 wih_f[2][4], whh_f[2][4][4];
    float bias1[2][4];
    int woff1[2];
#pragma unroll
    for (int ct = 0; ct < 2; ++ct) {
      const int colc = wbase + ct * 16 + lc;
      woff1[ct] = ((colc >> 3) * 4 + lg) * 8 + (colc & 7);
#pragma unroll
      for (int g = 0; g < 4; ++g) {
        const int n = g * 128 + colc;
        bias1[ct][g] = bih1[n] + bhh1[n];
        half8 f;
#pragma unroll
        for (int j = 0; j < 8; ++j) {
          const int k = lg * 8 + j;
          f[j] = (_Float16)((k < 19) ? Wih1[n * 19 + k] : 0.f);
        }
        wih_f[ct][g] = f;
#pragma unroll
        for (int kk = 0; kk < 4; ++kk) {
          const float* p = Whh1 + n * 128 + kk * 32 + lg * 8;
          half8 f2;
#pragma unroll
          for (int j = 0; j < 8; ++j) f2[j] = (_Float16)p[j];
          whh_f[ct][g][kk] = f2;
        }
      }
    }
    const bool yv = (lc < 7);
    const float ybias = (wv == 0 && yv) ? blin[lc] : 0.f;
    const _Float16* wlp = wils + (512 + lc) * 132 + lg * 8;
    const bool xv = (lg < 3);
    const _Float16* xpb = xp + (size_t)bid * 49152 + off0;
    half8 ax = {};
    if (xv) ax = *(const half8*)(xpb);   // t = 0
    float c1[2] = {0.f, 0.f};
    float* outp = out + (size_t)(bid * 4) * 3584 + lc;

#pragma unroll 1
    for (int it = 0; it < 513; ++it) {
      if (it < 512) {
        const _Float16* rd = h1b + (((it & 1) ^ 1) << 10) + off0;  // h1(t-1)
        const half8 hb0 = *(const half8*)(rd);
        const half8 hb1 = *(const half8*)(rd + 128);
        const half8 hb2 = *(const half8*)(rd + 256);
        const half8 hb3 = *(const half8*)(rd + 384);
        half8 axn = {};
        if (xv && it < 511) axn = *(const half8*)(xpb + (size_t)(it + 1) * 96);
        _Float16* wr = h1b + ((it & 1) << 10);
#pragma unroll
        for (int ct = 0; ct < 2; ++ct) {
          f32x4 a0 = MFMA16(ax, wih_f[ct][0], fz);
          f32x4 a1 = MFMA16(ax, wih_f[ct][1], fz);
          f32x4 a2 = MFMA16(ax, wih_f[ct][2], fz);
          f32x4 a3 = MFMA16(ax, wih_f[ct][3], fz);
          a0 = MFMA16(hb0, whh_f[ct][0][0], a0); a1 = MFMA16(hb0, whh_f[ct][1][0], a1);
          a2 = MFMA16(hb0, whh_f[ct][2][0], a2); a3 = MFMA16(hb0, whh_f[ct][3][0], a3);
          a0 = MFMA16(hb1, whh_f[ct][0][1], a0); a1 = MFMA16(hb1, whh_f[ct][1][1], a1);
          a2 = MFMA16(hb1, whh_f[ct][2][1], a2); a3 = MFMA16(hb1, whh_f[ct][3][1], a3);
          a0 = MFMA16(hb2, whh_f[ct][0][2], a0); a1 = MFMA16(hb2, whh_f[ct][1][2], a1);
          a2 = MFMA16(hb2, whh_f[ct][2][2], a2); a3 = MFMA16(hb2, whh_f[ct][3][2], a3);
          a0 = MFMA16(hb3, whh_f[ct][0][3], a0); a1 = MFMA16(hb3, whh_f[ct][1][3], a1);
          a2 = MFMA16(hb3, whh_f[ct][2][3], a2); a3 = MFMA16(hb3, whh_f[ct][3][3], a3);
          const float gi = sel4(a0, lg) + bias1[ct][0];
          const float gf = sel4(a1, lg) + bias1[ct][1];
          const float gg = sel4(a2, lg) + bias1[ct][2];
          const float go = sel4(a3, lg) + bias1[ct][3];
          const float I = sigf(gi), F = sigf(gf), G = tanhf_(gg), O = sigf(go);
          c1[ct] = F * c1[ct] + I * G;
          wr[woff1[ct]] = (_Float16)(O * tanhf_(c1[ct]));
        }
        ax = axn;
      }
      // y(it-2) from h2(it-2) (in h2b[it&1], stable this iteration)
      if (wv == 0 && it >= 2) {
        const _Float16* r2 = h2b + ((it & 1) << 10) + off0;
        const half8 y0 = *(const half8*)(r2);
        const half8 y1 = *(const half8*)(r2 + 128);
        const half8 y2 = *(const half8*)(r2 + 256);
        const half8 y3 = *(const half8*)(r2 + 384);
        const half8 wl0 = *(const half8*)(wlp);
        const half8 wl1 = *(const half8*)(wlp + 32);
        const half8 wl2 = *(const half8*)(wlp + 64);
        const half8 wl3 = *(const half8*)(wlp + 96);
        f32x4 ya = {ybias, ybias, ybias, ybias};
        ya = MFMA16(y0, wl0, ya);
        ya = MFMA16(y1, wl1, ya);
        ya = MFMA16(y2, wl2, ya);
        ya = MFMA16(y3, wl3, ya);
        if (lg == 0 && yv) {
#pragma unroll
          for (int j = 0; j < 4; ++j)
            outp[(size_t)j * 3584 + (size_t)(it - 2) * 7] = ya[j];
        }
      }
      BARRIER();
    }
    // final y(511): h2(511) lives in h2b[1]
    if (wv == 0) {
      const _Float16* r2 = h2b + 1024 + off0;
      const half8 y0 = *(const half8*)(r2);
      const half8 y1 = *(const half8*)(r2 + 128);
      const half8 y2 = *(const half8*)(r2 + 256);
      const half8 y3 = *(const half8*)(r2 + 384);
      const half8 wl0 = *(const half8*)(wlp);
      const half8 wl1 = *(const half8*)(wlp + 32);
      const half8 wl2 = *(const half8*)(wlp + 64);
      const half8 wl3 = *(const half8*)(wlp + 96);
      f32x4 ya = {ybias, ybias, ybias, ybias};
      ya = MFMA16(y0, wl0, ya);
      ya = MFMA16(y1, wl1, ya);
      ya = MFMA16(y2, wl2, ya);
      ya = MFMA16(y3, wl3, ya);
      if (lg == 0 && yv) {
#pragma unroll
        for (int j = 0; j < 4; ++j)
          outp[(size_t)j * 3584 + (size_t)511 * 7] = ya[j];
      }
    }
  } else {
    // ---------------- Layer-2 role (one step behind) ----------------
    const int wbase = (wv - 4) * 32;
    half8 whh_f[2][4][4];
    float bias2[2][4];
    int woff2[2];
#pragma unroll
    for (int ct = 0; ct < 2; ++ct) {
      const int colc = wbase + ct * 16 + lc;
      woff2[ct] = ((colc >> 3) * 4 + lg) * 8 + (colc & 7);
#pragma unroll
      for (int g = 0; g < 4; ++g) {
        const int n = g * 128 + colc;
        bias2[ct][g] = bih2[n] + bhh2[n];
#pragma unroll
        for (int kk = 0; kk < 4; ++kk) {
          const float* p = Whh2 + n * 128 + kk * 32 + lg * 8;
          half8 f2;
#pragma unroll
          for (int j = 0; j < 8; ++j) f2[j] = (_Float16)p[j];
          whh_f[ct][g][kk] = f2;
        }
      }
    }
    const _Float16* wp = wils + (wbase + lc) * 132 + lg * 8;
    float c2[2] = {0.f, 0.f};

#pragma unroll 1
    for (int it = 0; it < 513; ++it) {
      if (it >= 1) {
        // t2 = it-1: h1(t2) in h1b[(it-1)&1]; h2(t2-1) in h2b[it&1]
        const _Float16* rd1 = h1b + (((it & 1) ^ 1) << 10) + off0;
        const _Float16* rd2 = h2b + ((it & 1) << 10) + off0;
        const half8 p0 = *(const half8*)(rd1);
        const half8 p1 = *(const half8*)(rd1 + 128);
        const half8 p2 = *(const half8*)(rd1 + 256);
        const half8 p3 = *(const half8*)(rd1 + 384);
        const half8 q0 = *(const half8*)(rd2);
        const half8 q1 = *(const half8*)(rd2 + 128);
        const half8 q2 = *(const half8*)(rd2 + 256);
        const half8 q3 = *(const half8*)(rd2 + 384);
        _Float16* wr = h2b + (((it & 1) ^ 1) << 10);
#pragma unroll
        for (int ct = 0; ct < 2; ++ct) {
          f32x4 a[4];
#pragma unroll
          for (int g = 0; g < 4; ++g) {
            const _Float16* wgp = wp + (g * 128 + ct * 16) * 132;
            const half8 u0 = *(const half8*)(wgp);
            const half8 u1 = *(const half8*)(wgp + 32);
            const half8 u2 = *(const half8*)(wgp + 64);
            const half8 u3 = *(const half8*)(wgp + 96);
            f32x4 t = MFMA16(p0, u0, fz);
            t = MFMA16(p1, u1, t);
            t = MFMA16(p2, u2, t);
            t = MFMA16(p3, u3, t);
            t = MFMA16(q0, whh_f[ct][g][0], t);
            t = MFMA16(q1, whh_f[ct][g][1], t);
            t = MFMA16(q2, whh_f[ct][g][2], t);
            t = MFMA16(q3, whh_f[ct][g][3], t);
            a[g] = t;
          }
          const float gi = sel4(a[0], lg) + bias2[ct][0];
          const float gf = sel4(a[1], lg) + bias2[ct][1];
          const float gg = sel4(a[2], lg) + bias2[ct][2];
          const float go = sel4(a[3], lg) + bias2[ct][3];
          const float I = sigf(gi), F = sigf(gf), G = tanhf_(gg), O = sigf(go);
          c2[ct] = F * c2[ct] + I * G;
          wr[woff2[ct]] = (_Float16)(O * tanhf_(c2[ct]));
        }
      }
      BARRIER();
    }
  }
}

extern "C" void kernel_launch(void* const* d_in, const int* in_sizes, int n_in,
                              void* d_out, int out_size, void* d_ws, size_t ws_size,
                              hipStream_t stream) {
  (void)in_sizes; (void)n_in; (void)out_size; (void)ws_size;
  const float* x     = (const float*)d_in[0];
  const float* W_ih1 = (const float*)d_in[1];
  const float* W_hh1 = (const float*)d_in[2];
  const float* b_ih1 = (const float*)d_in[3];
  const float* b_hh1 = (const float*)d_in[4];
  const float* W_ih2 = (const float*)d_in[5];
  const float* W_hh2 = (const float*)d_in[6];
  const float* b_ih2 = (const float*)d_in[7];
  const float* b_hh2 = (const float*)d_in[8];
  const float* W_lin = (const float*)d_in[9];
  const float* b_lin = (const float*)d_in[10];
  float* out = (float*)d_out;
  _Float16* xpad = (_Float16*)d_ws;   // 256*512*96 halfs = 25,165,824 B

  xpad_kernel<<<6144, 256, 0, stream>>>(x, xpad);
  lstm_fused_kernel<<<256, 512, 0, stream>>>(xpad, W_ih1, W_hh1, b_ih1, b_hh1,
                                             W_ih2, W_hh2, b_ih2, b_hh2,
                                             W_lin, b_lin, out);
}